// Round 5
// baseline (74.925 us; speedup 1.0000x reference)
//
#include <hip/hip_runtime.h>

// ROIAlign 1D: feat (8,256,512) fp32, rois (2048,3), P=16, S=4 -> out (2048,256,16).
//
// R11 post-mortem: CRASH — LDS race in the deterministic compaction. Every
// thread wrote s_wcnt[0] = total while other waves were still READING
// s_wcnt[0..3] after the barrier -> late waves got corrupted c0/wbase/cnt ->
// Phase 4 read garbage meta (huge m.x) -> OOB global store -> core dump.
// Fix: total goes to a SEPARATE slot (s_tot) written by tid==0 only; the
// scanned slots s_wcnt[0..3] are read-only after the barrier. s_tot's
// visibility for Phase 4 is covered by the existing __syncthreads().
//
// Experiment unchanged (R11 theory, race-fixed):
//  1. DETERMINISTIC compaction: 4-wave LDS count + prefix scan. Meta order =
//     slot order, IDENTICAL across the 32 sibling ct-blocks of each (r,b) ->
//     siblings emit the same ROI-row sequence -> 512B chunks assemble
//     sequential 16KB rows at DRAM.
//  2. rois loads issued BEFORE feat loads: compaction's vmcnt wait leaves
//     feat loads in flight under ballot/scan VALU.
//  3. RSPLIT=8 (R9's best), unscaled tile + 1/S folded into fp16 weights.
// Layout: tile[q*512 + loc(t)] uint4 quad-channel fp16 tap-pairs,
// loc(t) = ((t&3)<<7)|(t>>2); staged writes lane-contiguous, reads keep
// t[4:2] bank entropy; gather = 2x ds_read_b128 + 8x v_dot2 per sample-quad.
// Pre-commitment: neutral vs 74.5 -> declare roofline next round.

#define T_DIM 512
#define CH    256
#define P_DIM 16
#define S_RAT 4
#define CTILE 8
#define NCT   (CH / CTILE)     // 32
#define RSPLIT 8
#define MAXSL  256             // ROI-slice length = 2048 / RSPLIT
#define MAXMETA 96             // Bin(256,1/8) max ~60; overflow prob ~1e-20

typedef _Float16 h2 __attribute__((ext_vector_type(2)));

__device__ __forceinline__ float dot2_acc(h2 a, h2 b, float c) {
#if __has_builtin(__builtin_amdgcn_fdot2)
    return __builtin_amdgcn_fdot2(a, b, c, false);
#else
    return fmaf((float)a.x, (float)b.x, fmaf((float)a.y, (float)b.y, c));
#endif
}

__device__ __forceinline__ unsigned pack2(float a, float b) {
    union { h2 h; unsigned u; } u;
    u.h = h2{(_Float16)a, (_Float16)b};
    return u.u;
}

__global__ __launch_bounds__(256) void roialign_lds_kernel(
    const float* __restrict__ feat,   // (8, 256, 512)
    const float* __restrict__ rois,   // (N, 3)
    float* __restrict__ out,          // (N, 256, 16)
    int N)
{
    // tile[q*512 + loc(t)]: uint4 = {pair(c=4q+0), pair(c+1), pair(c+2), pair(c+3)}
    // at tap t, UNSCALED fp16. 16 KB.
    __shared__ __align__(16) uint4 tile[2 * T_DIM];
    __shared__ float4 s_meta[MAXMETA];    // 1.5 KB
    __shared__ int    s_wcnt[4];          // per-wave match counts (read-only after barrier)
    __shared__ int    s_tot;              // total, written by tid==0 ONLY

    const int ct  = blockIdx.x;   // channel tile 0..31
    const int r   = blockIdx.y;   // ROI slice 0..RSPLIT-1
    const int b   = blockIdx.z;   // batch 0..7
    const int tid = threadIdx.x;
    const int wv  = tid >> 6;     // wave 0..3
    const int lane = tid & 63;

    // --- Phase 0: issue rois loads FIRST (oldest in vmcnt queue). ---
    const int ri = r * MAXSL + tid;
    float bf = -1.0f, sx = 0.0f, ex = 0.0f;
    if (ri < N) {
        bf = rois[3 * ri];
        sx = rois[3 * ri + 1];
        ex = rois[3 * ri + 2];
    }

    // --- Phase 1: issue feat loads (4 channels x f4 + neighbor), stay in flight. ---
    const int q = tid >> 7;        // 0..1: channel quad
    const int k = tid & 127;       // tap chunk: taps 4k..4k+3
    float4 v0, v1, v2, v3;
    float  n0, n1, n2, n3;
    {
        const float* base = feat + ((size_t)b * CH + ct * CTILE + 4 * q) * T_DIM;
        const int nidx = (4 * k + 4 < T_DIM) ? (4 * k + 4) : (T_DIM - 1); // k=127: junk tap 511
        v0 = ((const float4*)(base + 0 * T_DIM))[k];  n0 = (base + 0 * T_DIM)[nidx];
        v1 = ((const float4*)(base + 1 * T_DIM))[k];  n1 = (base + 1 * T_DIM)[nidx];
        v2 = ((const float4*)(base + 2 * T_DIM))[k];  n2 = (base + 2 * T_DIM)[nidx];
        v3 = ((const float4*)(base + 3 * T_DIM))[k];  n3 = (base + 3 * T_DIM)[nidx];
    }

    // --- Phase 2a: ballot + per-wave count (waits only the rois loads). ---
    const bool match = (ri < N) && ((int)bf == b);
    {
        unsigned long long mask = __ballot(match);
        const int tot = __popcll(mask);
        if (lane == 0) s_wcnt[wv] = tot;
        const int pre = __popcll(mask & ((1ull << lane) - 1ull));

        // Raw barrier: make s_wcnt visible without draining feat vmcnt
        // (__syncthreads would wait vmcnt(0)). Compile-time ordering.
        asm volatile("s_waitcnt lgkmcnt(0)" ::: "memory");
        __builtin_amdgcn_s_barrier();
        asm volatile("" ::: "memory");

        // --- Phase 2b: deterministic prefix over waves; slot-order compaction.
        //     s_wcnt[0..3] are READ-ONLY here; total goes to s_tot (tid 0).
        const int c0 = s_wcnt[0], c1 = s_wcnt[1], c2 = s_wcnt[2], c3 = s_wcnt[3];
        if (tid == 0) s_tot = c0 + c1 + c2 + c3;
        const int wbase = (wv > 0 ? c0 : 0) + (wv > 1 ? c1 : 0) + (wv > 2 ? c2 : 0);
        if (match) {
            const int pos = wbase + pre;
            if (pos < MAXMETA)
                s_meta[pos] = make_float4((float)ri, sx, ex, 0.0f);
        }
    }

    // --- Phase 3: pack (no scale) + write tile. Fixed j2 -> lanes write
    //     contiguous 16B (conflict-free ds_write_b128). Waits feat vmcnt here.
    {
        uint4* trow = &tile[q * T_DIM];
        trow[0 * 128 + k] = make_uint4(pack2(v0.x, v0.y), pack2(v1.x, v1.y),
                                       pack2(v2.x, v2.y), pack2(v3.x, v3.y));  // tap 4k+0
        trow[1 * 128 + k] = make_uint4(pack2(v0.y, v0.z), pack2(v1.y, v1.z),
                                       pack2(v2.y, v2.z), pack2(v3.y, v3.z));  // tap 4k+1
        trow[2 * 128 + k] = make_uint4(pack2(v0.z, v0.w), pack2(v1.z, v1.w),
                                       pack2(v2.z, v2.w), pack2(v3.z, v3.w));  // tap 4k+2
        trow[3 * 128 + k] = make_uint4(pack2(v0.w, n0), pack2(v1.w, n1),
                                       pack2(v2.w, n2), pack2(v3.w, n3));      // tap 4k+3
    }
    __syncthreads();   // all LDS (s_meta, s_tot, tile) visible from here
    const int cnt = min(s_tot, MAXMETA);

    // --- Phase 4: thread = (roi_slot, p); chunks of 16 ROIs, slot order
    //     identical across the 32 sibling ct-blocks -> sequential ROI rows.
    const int rs = tid >> 4;          // 0..15: ROI slot within chunk
    const int p  = tid & 15;          // 0..15: bin

    float qf[S_RAT];
#pragma unroll
    for (int s = 0; s < S_RAT; ++s)
        qf[s] = (float)p + ((float)s + 0.5f) * (1.0f / S_RAT);

    const char* tbase = (const char*)tile;

    for (int base2 = 0; base2 < cnt; base2 += 16) {
        const int i = base2 + rs;
        if (i >= cnt) break;          // rs fixed per thread: no re-entry

        const float4 m     = s_meta[i];
        const float  start = m.y;
        const float  bin   = fmaxf(m.z - start, 1.0f) * (1.0f / P_DIM);

        // Metadata ONCE for this (ROI, p): swizzled byte offset + scaled fp16 weights.
        int boff[S_RAT];
        h2  wp[S_RAT];
#pragma unroll
        for (int s = 0; s < S_RAT; ++s) {
            float x  = fmaf(qf[s], bin, start);            // x in [0,512) by construction
            float xc = fminf(x, (float)(T_DIM - 1));
            float tf = fminf(truncf(xc), (float)(T_DIM - 2));
            const int t = (int)tf;
            const float w = xc - tf;
            wp[s]   = h2{(_Float16)((1.0f - w) * (1.0f / S_RAT)),
                         (_Float16)(w * (1.0f / S_RAT))};  // 1/S folded into weights
            boff[s] = ((t & 3) << 11) | ((t >> 2) << 4);   // loc(t)*16
        }

        float* outn = out + (size_t)(int)m.x * (CH * P_DIM) + ct * (CTILE * P_DIM) + p;
#pragma unroll
        for (int qq = 0; qq < 2; ++qq) {
            float a0 = 0.0f, a1 = 0.0f, a2 = 0.0f, a3 = 0.0f;
#pragma unroll
            for (int s = 0; s < S_RAT; ++s) {
                const uint4 e = *(const uint4*)(tbase + qq * 8192 + boff[s]);
                union { unsigned u; h2 h; } c0, c1, c2, c3;
                c0.u = e.x; c1.u = e.y; c2.u = e.z; c3.u = e.w;
                a0 = dot2_acc(c0.h, wp[s], a0);
                a1 = dot2_acc(c1.h, wp[s], a1);
                a2 = dot2_acc(c2.h, wp[s], a2);
                a3 = dot2_acc(c3.h, wp[s], a3);
            }
            outn[(4 * qq + 0) * P_DIM] = a0;   // wave: 4 ROIs x 16 contig p = full lines
            outn[(4 * qq + 1) * P_DIM] = a1;
            outn[(4 * qq + 2) * P_DIM] = a2;
            outn[(4 * qq + 3) * P_DIM] = a3;
        }
    }
}

extern "C" void kernel_launch(void* const* d_in, const int* in_sizes, int n_in,
                              void* d_out, int out_size, void* d_ws, size_t ws_size,
                              hipStream_t stream) {
    const float* feat = (const float*)d_in[0];   // (8,256,512)
    const float* rois = (const float*)d_in[1];   // (N,3)
    float* out = (float*)d_out;                  // (N,256,16)
    const int N = in_sizes[1] / 3;               // 2048

    dim3 grid(NCT, RSPLIT, 8);                   // 2048 blocks
    roialign_lds_kernel<<<grid, dim3(256), 0, stream>>>(feat, rois, out, N);
}